// Round 1
// baseline (732.367 us; speedup 1.0000x reference)
//
#include <hip/hip_runtime.h>

// MFMA fragment types (per guide: 8 bf16 in 4 VGPRs as short8; 4 fp32 acc)
typedef __attribute__((ext_vector_type(8))) short bf16x8;
typedef __attribute__((ext_vector_type(4))) float f32x4;

#define ASTRIDE 72  // LDS row stride in bf16 elems: 64+8 pad -> max 2-way bank alias (free)

__device__ __forceinline__ short f2b(float f) {
    unsigned u = __float_as_uint(f);
    u += 0x7fffu + ((u >> 16) & 1u);  // round-to-nearest-even
    return (short)(u >> 16);
}

// B-operand fragment for mfma_f32_16x16x32_bf16: lane holds B[k=quad*8+j][n=lane&15] = W[n][k]
__device__ __forceinline__ bf16x8 load_bfrag(const float* __restrict__ W, int rows, int cols,
                                             int n0, int k0, int lane) {
    int n = n0 + (lane & 15);
    int kb = k0 + (lane >> 4) * 8;
    bf16x8 f;
#pragma unroll
    for (int j = 0; j < 8; ++j) {
        int k = kb + j;
        float w = (n < rows && k < cols) ? W[(size_t)n * cols + k] : 0.0f;
        f[j] = f2b(w);
    }
    return f;
}

__global__ void __launch_bounds__(256) nerf_fused(
    const float* __restrict__ hash, const float* __restrict__ sh,
    const float* __restrict__ d0, const float* __restrict__ d1,
    const float* __restrict__ c0, const float* __restrict__ c1,
    const float* __restrict__ c2, const float* __restrict__ c3,
    float* __restrict__ out, int ntiles, int iters)
{
    __shared__ short b0s[4][16 * ASTRIDE];
    __shared__ short b1s[4][16 * ASTRIDE];
    __shared__ float obs[4][16][4];

    const int lane = threadIdx.x & 63;
    const int wave = threadIdx.x >> 6;
    const int p = lane & 15;  // A-operand row (point) == C-operand col
    const int q = lane >> 4;  // quad

    short* __restrict__ b0 = b0s[wave];
    short* __restrict__ b1 = b1s[wave];
    float* __restrict__ ob = &obs[wave][0][0];

    // ---- preload all weights as register-resident B fragments (28 frags = 112 VGPRs) ----
    bf16x8 Bd0[4], Bc0[4], Bc1[4][2], Bc2[4][2], Bd1[2], Bc3[2];
#pragma unroll
    for (int t = 0; t < 4; ++t) {
        Bd0[t] = load_bfrag(d0, 64, 32, 16 * t, 0, lane);
        Bc0[t] = load_bfrag(c0, 64, 31, 16 * t, 0, lane);  // k=31 zero-padded
#pragma unroll
        for (int kk = 0; kk < 2; ++kk) {
            Bc1[t][kk] = load_bfrag(c1, 64, 64, 16 * t, 32 * kk, lane);
            Bc2[t][kk] = load_bfrag(c2, 64, 64, 16 * t, 32 * kk, lane);
        }
    }
    Bd1[0] = load_bfrag(d1, 16, 64, 0, 0, lane);
    Bd1[1] = load_bfrag(d1, 16, 64, 0, 32, lane);
    Bc3[0] = load_bfrag(c3, 3, 64, 0, 0, lane);  // rows 3..15 zero
    Bc3[1] = load_bfrag(c3, 3, 64, 0, 32, lane);

    const f32x4 zf = {0.f, 0.f, 0.f, 0.f};

    for (int it = 0; it < iters; ++it) {
        int tile = (it * (int)gridDim.x + (int)blockIdx.x) * 4 + wave;
        bool live = tile < ntiles;
        int m0 = (live ? tile : 0) * 16;

        // global loads: hash row for L1 A-frag, sh row staged into b1 cols [0,16)
        const float* hrow = hash + (size_t)(m0 + p) * 32 + q * 8;
        float4 h0 = *(const float4*)(hrow);
        float4 h1 = *(const float4*)(hrow + 4);
        float4 sv = *(const float4*)(sh + (size_t)(m0 + p) * 16 + q * 4);

        short4 spk;
        spk.x = f2b(sv.x); spk.y = f2b(sv.y); spk.z = f2b(sv.z); spk.w = f2b(sv.w);
        *(short4*)(&b1[p * ASTRIDE + q * 4]) = spk;
        if (q == 0) b1[p * ASTRIDE + 31] = 0;  // K-pad (concat dim 31 -> 32)

        // ---- L1: h = relu(hash @ d0^T), K=32, N=64 ----
        bf16x8 a1;
        a1[0] = f2b(h0.x); a1[1] = f2b(h0.y); a1[2] = f2b(h0.z); a1[3] = f2b(h0.w);
        a1[4] = f2b(h1.x); a1[5] = f2b(h1.y); a1[6] = f2b(h1.z); a1[7] = f2b(h1.w);
        f32x4 acc1[4];
#pragma unroll
        for (int t = 0; t < 4; ++t)
            acc1[t] = __builtin_amdgcn_mfma_f32_16x16x32_bf16(a1, Bd0[t], zf, 0, 0, 0);
#pragma unroll
        for (int t = 0; t < 4; ++t)
#pragma unroll
            for (int r = 0; r < 4; ++r)
                b0[(q * 4 + r) * ASTRIDE + t * 16 + p] = f2b(fmaxf(acc1[t][r], 0.f));
        __syncthreads();

        // ---- L2: i = h @ d1^T, K=64, N=16 (no relu). col0=sigma, cols1..15=density ----
        bf16x8 x0 = *(const bf16x8*)(&b0[p * ASTRIDE + q * 8]);
        bf16x8 x1 = *(const bf16x8*)(&b0[p * ASTRIDE + 32 + q * 8]);
        f32x4 acc2 = __builtin_amdgcn_mfma_f32_16x16x32_bf16(x0, Bd1[0], zf, 0, 0, 0);
        acc2 = __builtin_amdgcn_mfma_f32_16x16x32_bf16(x1, Bd1[1], acc2, 0, 0, 0);
        if (p == 0) {
#pragma unroll
            for (int r = 0; r < 4; ++r) ob[(q * 4 + r) * 4 + 3] = acc2[r];  // sigma
        } else {
#pragma unroll
            for (int r = 0; r < 4; ++r)
                b1[(q * 4 + r) * ASTRIDE + 15 + p] = f2b(acc2[r]);  // density -> cols 16..30
        }
        __syncthreads();

        // ---- L3: x = relu(concat(sh,density) @ c0^T), K=32(31+pad), N=64 ----
        bf16x8 a3 = *(const bf16x8*)(&b1[p * ASTRIDE + q * 8]);
        f32x4 acc3[4];
#pragma unroll
        for (int t = 0; t < 4; ++t)
            acc3[t] = __builtin_amdgcn_mfma_f32_16x16x32_bf16(a3, Bc0[t], zf, 0, 0, 0);
#pragma unroll
        for (int t = 0; t < 4; ++t)
#pragma unroll
            for (int r = 0; r < 4; ++r)
                b0[(q * 4 + r) * ASTRIDE + t * 16 + p] = f2b(fmaxf(acc3[t][r], 0.f));
        __syncthreads();

        // ---- L4: relu(x @ c1^T), K=64, N=64 ----
        bf16x8 y0 = *(const bf16x8*)(&b0[p * ASTRIDE + q * 8]);
        bf16x8 y1 = *(const bf16x8*)(&b0[p * ASTRIDE + 32 + q * 8]);
        f32x4 acc4[4];
#pragma unroll
        for (int t = 0; t < 4; ++t) {
            acc4[t] = __builtin_amdgcn_mfma_f32_16x16x32_bf16(y0, Bc1[t][0], zf, 0, 0, 0);
            acc4[t] = __builtin_amdgcn_mfma_f32_16x16x32_bf16(y1, Bc1[t][1], acc4[t], 0, 0, 0);
        }
#pragma unroll
        for (int t = 0; t < 4; ++t)
#pragma unroll
            for (int r = 0; r < 4; ++r)
                b1[(q * 4 + r) * ASTRIDE + t * 16 + p] = f2b(fmaxf(acc4[t][r], 0.f));
        __syncthreads();

        // ---- L5: relu(x @ c2^T), K=64, N=64 ----
        bf16x8 z0 = *(const bf16x8*)(&b1[p * ASTRIDE + q * 8]);
        bf16x8 z1 = *(const bf16x8*)(&b1[p * ASTRIDE + 32 + q * 8]);
        f32x4 acc5[4];
#pragma unroll
        for (int t = 0; t < 4; ++t) {
            acc5[t] = __builtin_amdgcn_mfma_f32_16x16x32_bf16(z0, Bc2[t][0], zf, 0, 0, 0);
            acc5[t] = __builtin_amdgcn_mfma_f32_16x16x32_bf16(z1, Bc2[t][1], acc5[t], 0, 0, 0);
        }
#pragma unroll
        for (int t = 0; t < 4; ++t)
#pragma unroll
            for (int r = 0; r < 4; ++r)
                b0[(q * 4 + r) * ASTRIDE + t * 16 + p] = f2b(fmaxf(acc5[t][r], 0.f));
        __syncthreads();

        // ---- L6: color = x @ c3^T, K=64, N=3 (cols 3..15 zero) ----
        bf16x8 w0 = *(const bf16x8*)(&b0[p * ASTRIDE + q * 8]);
        bf16x8 w1 = *(const bf16x8*)(&b0[p * ASTRIDE + 32 + q * 8]);
        f32x4 acc6 = __builtin_amdgcn_mfma_f32_16x16x32_bf16(w0, Bc3[0], zf, 0, 0, 0);
        acc6 = __builtin_amdgcn_mfma_f32_16x16x32_bf16(w1, Bc3[1], acc6, 0, 0, 0);
        if (p < 3) {
#pragma unroll
            for (int r = 0; r < 4; ++r) ob[(q * 4 + r) * 4 + p] = acc6[r];
        }
        __syncthreads();

        // ---- coalesced float4 store: out[m][0..2]=color, out[m][3]=sigma ----
        if (live && lane < 16) {
            float4 o = *(const float4*)(&ob[lane * 4]);
            *(float4*)(out + (size_t)(m0 + lane) * 4) = o;
        }
    }
}

extern "C" void kernel_launch(void* const* d_in, const int* in_sizes, int n_in,
                              void* d_out, int out_size, void* d_ws, size_t ws_size,
                              hipStream_t stream) {
    const float* hash = (const float*)d_in[0];
    const float* sh   = (const float*)d_in[1];
    const float* d0   = (const float*)d_in[2];
    const float* d1   = (const float*)d_in[3];
    const float* c0   = (const float*)d_in[4];
    const float* c1   = (const float*)d_in[5];
    const float* c2   = (const float*)d_in[6];
    const float* c3   = (const float*)d_in[7];
    float* out = (float*)d_out;

    int n = in_sizes[0] / 32;          // 2097152
    int ntiles = (n + 15) / 16;        // 131072
    int grid = 2048;                   // 4 wave-tiles per block -> 16 grid-stride iters
    int iters = (ntiles + grid * 4 - 1) / (grid * 4);

    hipLaunchKernelGGL(nerf_fused, dim3(grid), dim3(256), 0, stream,
                       hash, sh, d0, d1, c0, c1, c2, c3, out, ntiles, iters);
}